// Round 2
// baseline (775.812 us; speedup 1.0000x reference)
//
#include <hip/hip_runtime.h>
#include <stdint.h>

typedef unsigned short u16;

#define NB 4
#define NN 128
#define NF 32
#define ND 64
#define NMAT (NB*ND*NN*NN)   // 4,194,304 elements

// ---- workspace byte offsets ----
#define OFF_A     0u           // fp32 [4][128][128]
#define OFF_ACC   262144u      // fp32 [4] (+pad)
#define OFF_AAT   262400u      // fp32 [4][128][128]
#define OFF_RA    524544u      // fp32 [4][128]
#define OFF_W     526592u      // fp32 [2][1152][64]
#define OFF_RM    1116416u     // fp32 [4][64][128]
#define OFF_CM    1247488u
#define OFF_RX    1378560u
#define OFF_CX    1509632u
#define OFF_X1    1640704u     // bf16 NMAT
#define OFF_X2    10029312u    // bf16 NMAT
#define OFF_UA    18417920u    // bf16 NMAT
#define OFF_UB    26806528u
#define OFF_UC    35195136u
#define OFF_UD    43583744u
#define OFF_YACC  51972352u    // fp32 NMAT   (end = 68,749,568)
#define OFF_FLAG  68749568u    // int (pad 256)
#define OFF_XF    68749824u    // fp32 16384
#define OFF_EWF   68815360u    // fp32 8192
#define OFF_CF    68848128u    // fp32 2*81920
#define OFF_BF    69503488u    // fp32 128   (end = 69,504,000)

__device__ __forceinline__ float b2f(u16 v){
  union { uint32_t u; float f; } x; x.u = ((uint32_t)v) << 16; return x.f;
}
__device__ __forceinline__ u16 f2b(float f){
  union { uint32_t u; float f2; } x; x.f2 = f;
  uint32_t u = x.u;
  return (u16)((u + 0x7FFFu + ((u >> 16) & 1u)) >> 16);
}

// slot -> reference op index mapping for W pack
__device__ __constant__ signed char dR1[18] = {0,9,1,10,2,3,4,13,14,19,5,7,15,18,6,8,16,17};
__device__ __constant__ signed char dR2[18] = {-1,11,-1,12,-1,-1,-1,-1,-1,-1,-1,-1,-1,-1,-1,-1,-1,-1};

// ---- dtype detect: bf16 N(0,1) data never has exponent >= 0x90 (|v|>=2^17);
// fp32 data read as u16 halves hits it with ~44% per low half-word. ----
__global__ void k_detect(const u16* __restrict__ x16, int* __restrict__ flag){
  int t = threadIdx.x;
  int hit = 0;
  for (int k = t; k < 16384; k += 256){
    u16 u = x16[k];
    int e = (u >> 7) & 0xFF;
    if (e >= 0x90) hit = 1;
  }
  if (hit) atomicOr(flag, 1);
}

// ---- normalize all float inputs to canonical fp32 ----
__global__ void k_convert(const void* __restrict__ xs, const void* __restrict__ ews,
                          const void* __restrict__ c1s, const void* __restrict__ c2s,
                          const void* __restrict__ b1s, const void* __restrict__ b2s,
                          const int* __restrict__ flag,
                          float* __restrict__ xf, float* __restrict__ ewf,
                          float* __restrict__ cf, float* __restrict__ bfv){
  int t = blockIdx.x*256 + threadIdx.x;
  if (t >= 188544) return;
  int isf = *flag;
  const void* src; int idx; float* dst;
  if (t < 16384)      { src = xs;  idx = t;          dst = xf + idx; }
  else if (t < 24576) { src = ews; idx = t - 16384;  dst = ewf + idx; }
  else if (t < 106496){ src = c1s; idx = t - 24576;  dst = cf + idx; }
  else if (t < 188416){ src = c2s; idx = t - 106496; dst = cf + 81920 + idx; }
  else if (t < 188480){ src = b1s; idx = t - 188416; dst = bfv + idx; }
  else                { src = b2s; idx = t - 188480; dst = bfv + 64 + idx; }
  float v = isf ? ((const float*)src)[idx] : b2f(((const u16*)src)[idx]);
  *dst = v;
}

// ---- A scatter ----
__global__ void k_scatter(const int* __restrict__ ei, const int* __restrict__ bat,
                          const float* __restrict__ ew, float* __restrict__ A, int E){
  int t = blockIdx.x*256 + threadIdx.x;
  if (t >= E) return;
  int s = ei[t], dnode = ei[E + t];
  int g = bat[s];
  int r = s - g*NN, c = dnode - g*NN;
  atomicAdd(&A[(g*NN + r)*NN + c], ew[t]);
}

// ---- rowsum of A ----
__global__ void k_rA(const float* __restrict__ A, float* __restrict__ rA){
  int b = blockIdx.x, i = threadIdx.x;
  const float* Ab = A + (b*NN + i)*NN;
  float s = 0.f;
  for (int j = 0; j < NN; j++) s += Ab[j];
  rA[b*NN + i] = s;
}

// ---- AAt[b] = A A^T ----
__global__ __launch_bounds__(256) void k_AAt(const float* __restrict__ A, float* __restrict__ AAt){
  int b = blockIdx.y, iq = blockIdx.x;           // iq 0..7
  int t = threadIdx.x;
  int j = t & 127, ih = t >> 7;                  // ih 0..1
  const float* Ab = A + b*NN*NN;
  float acc[8] = {0,0,0,0,0,0,0,0};
  for (int k = 0; k < NN; k++){
    float aj = Ab[j*NN + k];
    #pragma unroll
    for (int ii = 0; ii < 8; ii++){
      int i = iq*16 + ih*8 + ii;
      acc[ii] += Ab[i*NN + k] * aj;
    }
  }
  #pragma unroll
  for (int ii = 0; ii < 8; ii++){
    int i = iq*16 + ih*8 + ii;
    AAt[(b*NN + i)*NN + j] = acc[ii];
  }
}

// ---- materialize layer-1 input X1[b][d][i][j] (bf16) from canonical fp32 x ----
__global__ void k_makeX1(const float* __restrict__ xf, u16* __restrict__ X1){
  int idx = blockIdx.x*256 + threadIdx.x;
  if (idx >= NMAT) return;
  int j = idx & 127, i = (idx >> 7) & 127, d = (idx >> 14) & 63, b = idx >> 20;
  float v = (d < NF) ? xf[(b*NN + i)*NF + d] : xf[(b*NN + j)*NF + (d - NF)];
  X1[idx] = f2b(v);
}

// ---- build packed weight matrices W[2][1152][64] from canonical fp32 coeffs ----
__global__ void k_buildW(const float* __restrict__ cf, float* __restrict__ W){
  int gl = blockIdx.x*256 + threadIdx.x;
  if (gl >= 2*1152*64) return;
  int L = gl / (1152*64);
  int rem = gl - L*1152*64;
  int row = rem >> 6, e = rem & 63;
  int slot = row >> 6, d = row & 63;
  const float* cc = cf + L*81920;
  int base = (d*64 + e)*20;
  float v = cc[base + dR1[slot]];
  if (dR2[slot] >= 0) v += cc[base + dR2[slot]];
  float scale = (slot == 9) ? 1.0f : (1.0f/128.0f);
  W[gl] = v * scale;
}

// ---- per-(b,d) row/col sums of M=X*A and X ----
__global__ void k_rowcol(const u16* __restrict__ X, const float* __restrict__ A,
                         float* __restrict__ RM, float* __restrict__ CM,
                         float* __restrict__ RX, float* __restrict__ CXv){
  int d = blockIdx.x, b = blockIdx.y;
  int j = threadIdx.x;                       // 128 threads
  const u16* Xp = X + (size_t)(b*ND + d)*NN*NN;
  const float* Ap = A + b*NN*NN;
  float cm = 0.f, cx = 0.f;
  for (int i = 0; i < NN; i++){
    float xv = b2f(Xp[i*NN + j]);
    float av = Ap[i*NN + j];
    cm += xv*av; cx += xv;
  }
  CM[(b*ND + d)*NN + j] = cm;
  CXv[(b*ND + d)*NN + j] = cx;
  int i = j;
  float rm = 0.f, rx = 0.f;
  for (int jj = 0; jj < NN; jj++){
    float xv = b2f(Xp[i*NN + jj]);
    float av = Ap[i*NN + jj];
    rm += xv*av; rx += xv;
  }
  RM[(b*ND + d)*NN + i] = rm;
  RX[(b*ND + d)*NN + i] = rx;
}

// ---- channel-mix: produce Ua,Ub,Uc,Ud (bf16) and pointwise part into Yacc (fp32) ----
__global__ __launch_bounds__(256) void k_mix(const u16* __restrict__ X, const float* __restrict__ A,
    const float* __restrict__ AAt, const float* __restrict__ rA, const float* __restrict__ W,
    u16* __restrict__ Ua, u16* __restrict__ Ub, u16* __restrict__ Uc, u16* __restrict__ Ud,
    float* __restrict__ Yacc)
{
  const int i = blockIdx.x, b = blockIdx.y, g = blockIdx.z;
  __shared__ float lx[16][128];
  __shared__ float lw[4][16][64];
  const int t = threadIdx.x;
  const int jq = t & 31, j0 = jq*4;
  const int e0 = (t >> 5) * 8;

  const float4 a4  = *(const float4*)(A   + (b*NN + i)*NN + j0);
  const float4 t4  = *(const float4*)(AAt + (b*NN + i)*NN + j0);
  const float4 rj4 = *(const float4*)(rA + b*NN + j0);
  const float ri = rA[b*NN + i];
  const float4 one4 = make_float4(1.f,1.f,1.f,1.f);
  const float4 ri4  = make_float4(ri,ri,ri,ri);

  int nslots; int offs[4]; float4 scal[4];
  switch (g){
    case 0: nslots=2; offs[0]=0;   offs[1]=64;  offs[2]=0; offs[3]=0; scal[0]=a4; scal[1]=one4; scal[2]=one4; scal[3]=one4; break;
    case 1: nslots=2; offs[0]=128; offs[1]=192; offs[2]=0; offs[3]=0; scal[0]=a4; scal[1]=one4; scal[2]=one4; scal[3]=one4; break;
    case 2: nslots=1; offs[0]=256; offs[1]=0;   offs[2]=0; offs[3]=0; scal[0]=a4; scal[1]=one4; scal[2]=one4; scal[3]=one4; break;
    case 3: nslots=1; offs[0]=320; offs[1]=0;   offs[2]=0; offs[3]=0; scal[0]=a4; scal[1]=one4; scal[2]=one4; scal[3]=one4; break;
    default: nslots=4; offs[0]=384; offs[1]=448; offs[2]=512; offs[3]=576;
             scal[0]=t4; scal[1]=ri4; scal[2]=rj4; scal[3]=one4; break;
  }

  float acc[8][4];
  #pragma unroll
  for (int ee = 0; ee < 8; ee++){ acc[ee][0]=0.f; acc[ee][1]=0.f; acc[ee][2]=0.f; acc[ee][3]=0.f; }

  for (int d0 = 0; d0 < ND; d0 += 16){
    {
      int dd = t >> 4, seg = t & 15;
      const u16* xp = X + (size_t)(((b*ND + d0 + dd)*NN + i)*NN + seg*8);
      uint4 raw = *(const uint4*)xp;
      float* dst = &lx[dd][seg*8];
      dst[0]=b2f((u16)(raw.x & 0xffffu)); dst[1]=b2f((u16)(raw.x >> 16));
      dst[2]=b2f((u16)(raw.y & 0xffffu)); dst[3]=b2f((u16)(raw.y >> 16));
      dst[4]=b2f((u16)(raw.z & 0xffffu)); dst[5]=b2f((u16)(raw.z >> 16));
      dst[6]=b2f((u16)(raw.w & 0xffffu)); dst[7]=b2f((u16)(raw.w >> 16));
    }
    for (int s = 0; s < nslots; s++)
      for (int l = t; l < 1024; l += 256){
        int dd = l >> 6, e = l & 63;
        lw[s][dd][e] = W[(offs[s] + d0 + dd)*64 + e];
      }
    __syncthreads();
    #pragma unroll
    for (int dd = 0; dd < 16; dd++){
      float4 x4 = *(const float4*)&lx[dd][j0];
      for (int s = 0; s < nslots; s++){
        float ax = x4.x*scal[s].x, ay = x4.y*scal[s].y, az = x4.z*scal[s].z, aw = x4.w*scal[s].w;
        const float* wp = &lw[s][dd][e0];
        float4 wlo = *(const float4*)wp;
        float4 whi = *(const float4*)(wp + 4);
        float wv[8] = {wlo.x,wlo.y,wlo.z,wlo.w,whi.x,whi.y,whi.z,whi.w};
        #pragma unroll
        for (int ee = 0; ee < 8; ee++){
          acc[ee][0] += ax*wv[ee];
          acc[ee][1] += ay*wv[ee];
          acc[ee][2] += az*wv[ee];
          acc[ee][3] += aw*wv[ee];
        }
      }
    }
    __syncthreads();
  }

  if (g < 4){
    u16* U = (g==0)?Ua:(g==1)?Ub:(g==2)?Uc:Ud;
    #pragma unroll
    for (int ee = 0; ee < 8; ee++){
      u16* op = U + (size_t)(((b*ND + e0 + ee)*NN + i)*NN + j0);
      ushort4 pk;
      pk.x = f2b(acc[ee][0]); pk.y = f2b(acc[ee][1]);
      pk.z = f2b(acc[ee][2]); pk.w = f2b(acc[ee][3]);
      *(ushort4*)op = pk;
    }
  } else {
    #pragma unroll
    for (int ee = 0; ee < 8; ee++){
      float* yp = Yacc + (size_t)(((b*ND + e0 + ee)*NN + i)*NN + j0);
      *(float4*)yp = make_float4(acc[ee][0], acc[ee][1], acc[ee][2], acc[ee][3]);
    }
  }
}

// ---- four A-products, all TN form C[i,j] += sum_k S[k,i]*R[k,j], accumulated into Yacc ----
__global__ __launch_bounds__(256) void k_tn(const float* __restrict__ A,
    const u16* __restrict__ Ua, const u16* __restrict__ Ub,
    const u16* __restrict__ Uc, const u16* __restrict__ Ud,
    float* __restrict__ Yacc)
{
  const int bx = blockIdx.x;
  const int be = bx >> 1, ih = bx & 1;
  const int b = be >> 6;
  __shared__ float ls[8][128], lr[8][128];
  const int t = threadIdx.x;
  const int jq = t & 31, j0 = jq*4;
  const int io = t >> 5;
  const int ibase = ih*64 + io*8;
  float acc[8][4];
  #pragma unroll
  for (int ii = 0; ii < 8; ii++){ acc[ii][0]=0.f; acc[ii][1]=0.f; acc[ii][2]=0.f; acc[ii][3]=0.f; }
  const float* Ab = A + b*NN*NN;

  #pragma unroll 1
  for (int f = 0; f < 4; f++){
    const u16* U = ((f==0)?Ua:(f==1)?Ub:(f==2)?Uc:Ud) + ((size_t)be << 14);
    for (int k0 = 0; k0 < NN; k0 += 8){
      if (f == 0 || f == 1){
        float* du = (f==0) ? &ls[0][0] : &lr[0][0];
        float* da = (f==0) ? &lr[0][0] : &ls[0][0];
        for (int l = t; l < 1024; l += 256){
          int kk = l >> 7, col = l & 127;
          du[kk*128 + col] = b2f(U[(k0 + kk)*NN + col]);
          da[kk*128 + col] = Ab[(k0 + kk)*NN + col];
        }
      } else {
        float* du = (f==2) ? &ls[0][0] : &lr[0][0];
        float* da = (f==2) ? &lr[0][0] : &ls[0][0];
        {
          int c = t >> 1, half = t & 1;
          ushort4 raw = *(const ushort4*)(U + c*NN + k0 + half*4);
          du[(half*4 + 0)*128 + c] = b2f(raw.x);
          du[(half*4 + 1)*128 + c] = b2f(raw.y);
          du[(half*4 + 2)*128 + c] = b2f(raw.z);
          du[(half*4 + 3)*128 + c] = b2f(raw.w);
        }
        for (int l = t; l < 1024; l += 256){
          int kk = l >> 7, col = l & 127;
          da[kk*128 + col] = Ab[(k0 + kk)*NN + col];
        }
      }
      __syncthreads();
      #pragma unroll
      for (int kk = 0; kk < 8; kk++){
        const float* sp = &ls[kk][ibase];
        float4 s0 = *(const float4*)sp, s1 = *(const float4*)(sp + 4);
        float4 r4 = *(const float4*)&lr[kk][j0];
        float sv[8] = {s0.x,s0.y,s0.z,s0.w,s1.x,s1.y,s1.z,s1.w};
        #pragma unroll
        for (int ii = 0; ii < 8; ii++){
          acc[ii][0] += sv[ii]*r4.x;
          acc[ii][1] += sv[ii]*r4.y;
          acc[ii][2] += sv[ii]*r4.z;
          acc[ii][3] += sv[ii]*r4.w;
        }
      }
      __syncthreads();
    }
  }
  #pragma unroll
  for (int ii = 0; ii < 8; ii++){
    float* yp = Yacc + ((size_t)be << 14) + (ibase + ii)*NN + j0;
    float4 y = *(float4*)yp;
    y.x += acc[ii][0]; y.y += acc[ii][1]; y.z += acc[ii][2]; y.w += acc[ii][3];
    *(float4*)yp = y;
  }
}

// ---- epilogue: add broadcast terms + bias; sigmoid->X2 (layer1) or reduce to acc4 (layer2) ----
__global__ __launch_bounds__(256) void k_epi(const float* __restrict__ Yacc, const float* __restrict__ W,
    const float* __restrict__ RM, const float* __restrict__ CM,
    const float* __restrict__ RX, const float* __restrict__ CXv,
    const float* __restrict__ bias, u16* __restrict__ Xout, float* __restrict__ acc4, int last)
{
  const int be = blockIdx.x;
  const int b = be >> 6, e = be & 63;
  __shared__ float radd[128], cadd[128];
  __shared__ float red[4];
  const int t = threadIdx.x;
  if (t < 128){
    int i = t; float s = 0.f;
    for (int d = 0; d < ND; d++){
      int v = (b*ND + d)*NN + i;
      s += W[(640 + d)*64 + e]*RM[v] + W[(704 + d)*64 + e]*CM[v]
         + W[(768 + d)*64 + e]*RX[v] + W[(832 + d)*64 + e]*CXv[v];
    }
    radd[i] = s;
  } else {
    int j = t - 128; float s = 0.f;
    for (int d = 0; d < ND; d++){
      int v = (b*ND + d)*NN + j;
      s += W[(896 + d)*64 + e]*RM[v] + W[(960 + d)*64 + e]*CM[v]
         + W[(1024 + d)*64 + e]*RX[v] + W[(1088 + d)*64 + e]*CXv[v];
    }
    cadd[j] = s;
  }
  __syncthreads();
  const float bv = bias[e];
  const float* Y = Yacc + ((size_t)be << 14);
  if (!last){
    u16* Xo = Xout + ((size_t)be << 14);
    for (int l = 0; l < 64; l++){
      int idx = l*256 + t;
      int ii = idx >> 7, jj = idx & 127;
      float v = Y[idx] + radd[ii] + cadd[jj] + bv;
      v = 1.f/(1.f + __expf(-v));
      Xo[idx] = f2b(v);
    }
  } else {
    float loc = 0.f;
    for (int l = 0; l < 64; l++){
      int idx = l*256 + t;
      int ii = idx >> 7, jj = idx & 127;
      loc += Y[idx] + radd[ii] + cadd[jj] + bv;
    }
    for (int off = 32; off > 0; off >>= 1) loc += __shfl_down(loc, off, 64);
    if ((t & 63) == 0) red[t >> 6] = loc;
    __syncthreads();
    if (t == 0) atomicAdd(&acc4[b], red[0] + red[1] + red[2] + red[3]);
  }
}

__global__ void k_finish(const float* __restrict__ acc4, const int* __restrict__ flag,
                         void* __restrict__ out){
  int b = threadIdx.x;
  if (b >= NB) return;
  float v = acc4[b] * (1.0f/1048576.0f);  // mean over 64*128*128
  if (*flag) ((float*)out)[b] = v;
  else       ((u16*)out)[b] = f2b(v);
}

extern "C" void kernel_launch(void* const* d_in, const int* in_sizes, int n_in,
                              void* d_out, int out_size, void* d_ws, size_t ws_size,
                              hipStream_t stream)
{
  const void* x   = d_in[0];
  const void* ew  = d_in[1];
  const void* c1  = d_in[2];
  const void* b1  = d_in[3];
  const void* c2  = d_in[4];
  const void* b2  = d_in[5];
  const int* ei  = (const int*)d_in[6];
  const int* bat = (const int*)d_in[7];
  const int E = in_sizes[1];

  char* wsb = (char*)d_ws;
  float* A    = (float*)(wsb + OFF_A);
  float* acc4 = (float*)(wsb + OFF_ACC);
  float* AAt  = (float*)(wsb + OFF_AAT);
  float* rA   = (float*)(wsb + OFF_RA);
  float* W    = (float*)(wsb + OFF_W);
  float* RM   = (float*)(wsb + OFF_RM);
  float* CM   = (float*)(wsb + OFF_CM);
  float* RX   = (float*)(wsb + OFF_RX);
  float* CXv  = (float*)(wsb + OFF_CX);
  u16* X1 = (u16*)(wsb + OFF_X1);
  u16* X2 = (u16*)(wsb + OFF_X2);
  u16* Ua = (u16*)(wsb + OFF_UA);
  u16* Ub = (u16*)(wsb + OFF_UB);
  u16* Uc = (u16*)(wsb + OFF_UC);
  u16* Ud = (u16*)(wsb + OFF_UD);
  float* Yacc = (float*)(wsb + OFF_YACC);
  int*   flag = (int*)(wsb + OFF_FLAG);
  float* xf   = (float*)(wsb + OFF_XF);
  float* ewf  = (float*)(wsb + OFF_EWF);
  float* cf   = (float*)(wsb + OFF_CF);
  float* bfv  = (float*)(wsb + OFF_BF);

  hipMemsetAsync(wsb, 0, OFF_AAT, stream);              // zero A and acc4
  hipMemsetAsync(wsb + OFF_FLAG, 0, 256, stream);       // zero flag

  k_detect<<<dim3(1), dim3(256), 0, stream>>>((const u16*)x, flag);
  k_convert<<<dim3(737), dim3(256), 0, stream>>>(x, ew, c1, c2, b1, b2, flag, xf, ewf, cf, bfv);
  k_scatter<<<dim3((E + 255)/256), dim3(256), 0, stream>>>(ei, bat, ewf, A, E);
  k_rA<<<dim3(NB), dim3(128), 0, stream>>>(A, rA);
  k_AAt<<<dim3(8, NB), dim3(256), 0, stream>>>(A, AAt);
  k_makeX1<<<dim3(NMAT/256), dim3(256), 0, stream>>>(xf, X1);
  k_buildW<<<dim3(576), dim3(256), 0, stream>>>(cf, W);

  for (int L = 0; L < 2; L++){
    const u16* Xc = L ? X2 : X1;
    const float* Wl = W + (size_t)L*1152*64;
    k_rowcol<<<dim3(ND, NB), dim3(128), 0, stream>>>(Xc, A, RM, CM, RX, CXv);
    k_mix<<<dim3(NN, NB, 5), dim3(256), 0, stream>>>(Xc, A, AAt, rA, Wl, Ua, Ub, Uc, Ud, Yacc);
    k_tn<<<dim3(512), dim3(256), 0, stream>>>(A, Ua, Ub, Uc, Ud, Yacc);
    k_epi<<<dim3(256), dim3(256), 0, stream>>>(Yacc, Wl, RM, CM, RX, CXv, bfv + L*64, X2, acc4, L);
  }
  k_finish<<<dim3(1), dim3(64), 0, stream>>>(acc4, flag, d_out);
}

// Round 3
// 516.885 us; speedup vs baseline: 1.5009x; 1.5009x over previous
//
#include <hip/hip_runtime.h>
#include <stdint.h>

typedef unsigned short u16;
using short8 = __attribute__((ext_vector_type(8))) short;
using f32x4  = __attribute__((ext_vector_type(4))) float;

#define NB 4
#define NN 128
#define NF 32
#define ND 64
#define NMAT (NB*ND*NN*NN)   // 4,194,304

// ---- workspace byte offsets ----
#define OFF_A     0u           // fp32 [4][16384]
#define OFF_ACC   262144u      // fp32 [4] (+pad)
#define OFF_AAT   262400u      // fp32 [4][16384]
#define OFF_RA    524544u      // fp32 [4][128]
#define OFF_W     526592u      // fp32 [2][1152][64]
#define OFF_RM    1116416u     // fp32 [4][64][128]
#define OFF_CM    1247488u
#define OFF_RX    1378560u
#define OFF_CX    1509632u
#define OFF_FLAG  1640704u     // int (+pad)
#define OFF_BF    1640960u     // fp32 128 (+pad)
#define OFF_ATB   1641472u     // bf16 [4][128n][128k]  (A^T, k-contig)
#define OFF_WB    1772544u     // bf16 [2][10][64e][64d]
#define OFF_X2    1936384u     // bf16 NMAT   (aliases UAT)
#define OFF_XT    10324992u    // bf16 [4][16384 ij][64 d]  (aliases UBT)
#define OFF_UA    18713600u    // bf16 NMAT
#define OFF_UB    27102208u
#define OFF_UC    35490816u
#define OFF_UD    43879424u
#define OFF_YACC  52268032u    // fp32 NMAT  (end 69,045,248)
// convert scratch aliased INTO Yacc region (dead before first Yacc write):
#define OFF_XF    (OFF_YACC)            // fp32 16384
#define OFF_EWF   (OFF_YACC + 65536u)   // fp32 8192
#define OFF_CF    (OFF_YACC + 98304u)   // fp32 2*81920
#define OFF_UAT   OFF_X2
#define OFF_UBT   OFF_XT

__device__ __forceinline__ float b2f(u16 v){
  union { uint32_t u; float f; } x; x.u = ((uint32_t)v) << 16; return x.f;
}
__device__ __forceinline__ u16 f2b(float f){
  union { uint32_t u; float f2; } x; x.f2 = f;
  uint32_t u = x.u;
  return (u16)((u + 0x7FFFu + ((u >> 16) & 1u)) >> 16);
}

#define MFMA16(a,b,c) __builtin_amdgcn_mfma_f32_16x16x32_bf16((a),(b),(c),0,0,0)

__device__ __constant__ signed char dR1[18] = {0,9,1,10,2,3,4,13,14,19,5,7,15,18,6,8,16,17};
__device__ __constant__ signed char dR2[18] = {-1,11,-1,12,-1,-1,-1,-1,-1,-1,-1,-1,-1,-1,-1,-1,-1,-1};

// ---- dtype detect (kept for robustness; round-2 proved bf16 but cheap) ----
__global__ void k_detect(const u16* __restrict__ x16, int* __restrict__ flag){
  int t = threadIdx.x;
  int hit = 0;
  for (int k = t; k < 16384; k += 256){
    u16 u = x16[k];
    int e = (u >> 7) & 0xFF;
    if (e >= 0x90) hit = 1;
  }
  if (hit) atomicOr(flag, 1);
}

__global__ void k_convert(const void* __restrict__ xs, const void* __restrict__ ews,
                          const void* __restrict__ c1s, const void* __restrict__ c2s,
                          const void* __restrict__ b1s, const void* __restrict__ b2s,
                          const int* __restrict__ flag,
                          float* __restrict__ xf, float* __restrict__ ewf,
                          float* __restrict__ cf, float* __restrict__ bfv){
  int t = blockIdx.x*256 + threadIdx.x;
  if (t >= 188544) return;
  int isf = *flag;
  const void* src; int idx; float* dst;
  if (t < 16384)      { src = xs;  idx = t;          dst = xf + idx; }
  else if (t < 24576) { src = ews; idx = t - 16384;  dst = ewf + idx; }
  else if (t < 106496){ src = c1s; idx = t - 24576;  dst = cf + idx; }
  else if (t < 188416){ src = c2s; idx = t - 106496; dst = cf + 81920 + idx; }
  else if (t < 188480){ src = b1s; idx = t - 188416; dst = bfv + idx; }
  else                { src = b2s; idx = t - 188480; dst = bfv + 64 + idx; }
  float v = isf ? ((const float*)src)[idx] : b2f(((const u16*)src)[idx]);
  *dst = v;
}

__global__ void k_scatter(const int* __restrict__ ei, const int* __restrict__ bat,
                          const float* __restrict__ ew, float* __restrict__ A, int E){
  int t = blockIdx.x*256 + threadIdx.x;
  if (t >= E) return;
  int s = ei[t], dnode = ei[E + t];
  int g = bat[s];
  int r = s - g*NN, c = dnode - g*NN;
  atomicAdd(&A[(g*NN + r)*NN + c], ew[t]);
}

__global__ void k_rA(const float* __restrict__ A, float* __restrict__ rA){
  int b = blockIdx.x, i = threadIdx.x;
  const float* Ab = A + (b*NN + i)*NN;
  float s = 0.f;
  for (int j = 0; j < NN; j++) s += Ab[j];
  rA[b*NN + i] = s;
}

__global__ __launch_bounds__(256) void k_AAt(const float* __restrict__ A, float* __restrict__ AAt){
  int b = blockIdx.y, iq = blockIdx.x;
  int t = threadIdx.x;
  int j = t & 127, ih = t >> 7;
  const float* Ab = A + b*NN*NN;
  float acc[8] = {0,0,0,0,0,0,0,0};
  for (int k = 0; k < NN; k++){
    float aj = Ab[j*NN + k];
    #pragma unroll
    for (int ii = 0; ii < 8; ii++){
      int i = iq*16 + ih*8 + ii;
      acc[ii] += Ab[i*NN + k] * aj;
    }
  }
  #pragma unroll
  for (int ii = 0; ii < 8; ii++){
    int i = iq*16 + ih*8 + ii;
    AAt[(b*NN + i)*NN + j] = acc[ii];
  }
}

// ---- ATb[b][n][k] = bf16(A[b][k][n])  (k-contiguous transposed A) ----
__global__ __launch_bounds__(256) void k_at(const float* __restrict__ A, u16* __restrict__ ATb){
  int b = blockIdx.x;
  __shared__ float lds[128][129];
  int t = threadIdx.x;
  for (int l = 0; l < 64; l++){
    int idx = l*256 + t;
    lds[idx >> 7][idx & 127] = A[b*16384 + idx];
  }
  __syncthreads();
  for (int l = 0; l < 64; l++){
    int idx = l*256 + t;
    int r = idx >> 7, c = idx & 127;
    ATb[b*16384 + idx] = f2b(lds[c][r]);
  }
}

// ---- layer-1 Xt[b][ij][d] directly from x (d-contiguous, both sides coalesced) ----
__global__ void k_makeXt1(const float* __restrict__ xf, u16* __restrict__ Xt){
  int idx = blockIdx.x*256 + threadIdx.x;
  if (idx >= NMAT) return;
  int d = idx & 63, ij = (idx >> 6) & 16383, b = idx >> 20;
  int i = ij >> 7, j = ij & 127;
  float v = (d < NF) ? xf[(b*NN + i)*NF + d] : xf[(b*NN + j)*NF + (d - NF)];
  Xt[idx] = f2b(v);
}

// ---- X[b][e][ij] -> Xt[b][ij][e] via LDS tiles ----
__global__ __launch_bounds__(256) void k_xt(const u16* __restrict__ X, u16* __restrict__ Xt){
  int b = blockIdx.y;
  int ij0 = blockIdx.x*64;
  __shared__ u16 lds[64][65];
  int t = threadIdx.x;
  #pragma unroll
  for (int l = 0; l < 2; l++){
    int idx = l*2048 + t*8;
    int d = idx >> 6, c = idx & 63;
    const u16* p = X + ((size_t)(b*64 + d))*16384 + ij0 + c;
    short8 v = *(const short8*)p;
    #pragma unroll
    for (int k = 0; k < 8; k++) lds[d][c + k] = (u16)v[k];
  }
  __syncthreads();
  #pragma unroll
  for (int l = 0; l < 2; l++){
    int idx = l*2048 + t*8;
    int r = idx >> 6, c = idx & 63;
    short8 v;
    #pragma unroll
    for (int k = 0; k < 8; k++) v[k] = (short)lds[c + k][r];
    *(short8*)(Xt + ((size_t)(b*16384 + ij0 + r))*64 + c) = v;
  }
}

// ---- per-be 128x128 transpose: Ua->UaT, Ub->UbT ----
__global__ __launch_bounds__(256) void k_ut(const u16* __restrict__ Ua, const u16* __restrict__ Ub,
                                            u16* __restrict__ UaT, u16* __restrict__ UbT){
  int be = blockIdx.x;
  const u16* src = blockIdx.y ? Ub : Ua;
  u16* dst = blockIdx.y ? UbT : UaT;
  src += ((size_t)be) << 14; dst += ((size_t)be) << 14;
  __shared__ u16 lds[128][129];
  int t = threadIdx.x;
  #pragma unroll
  for (int l = 0; l < 8; l++){
    int idx = l*2048 + t*8;
    int r = idx >> 7, c = idx & 127;
    short8 v = *(const short8*)(src + r*128 + c);
    #pragma unroll
    for (int k = 0; k < 8; k++) lds[r][c + k] = (u16)v[k];
  }
  __syncthreads();
  #pragma unroll
  for (int l = 0; l < 8; l++){
    int idx = l*2048 + t*8;
    int r = idx >> 7, c = idx & 127;
    short8 v;
    #pragma unroll
    for (int k = 0; k < 8; k++) v[k] = (short)lds[c + k][r];
    *(short8*)(dst + r*128 + c) = v;
  }
}

// ---- W fp32 (all 18 slot-rows) + bf16 Wb[L][slot<10][e][d] (d-contiguous) ----
__global__ void k_buildW(const float* __restrict__ cf, float* __restrict__ W, u16* __restrict__ Wb){
  int gl = blockIdx.x*256 + threadIdx.x;
  if (gl >= 2*1152*64) return;
  int L = gl / (1152*64);
  int rem = gl - L*1152*64;
  int row = rem >> 6, e = rem & 63;
  int slot = row >> 6, d = row & 63;
  const float* cc = cf + L*81920;
  int base = (d*64 + e)*20;
  float v = cc[base + dR1[slot]];
  if (dR2[slot] >= 0) v += cc[base + dR2[slot]];
  float scale = (slot == 9) ? 1.0f : (1.0f/128.0f);
  v *= scale;
  W[gl] = v;
  if (slot < 10)
    Wb[(((size_t)L*10 + slot)*64 + e)*64 + d] = f2b(v);
}

// ---- row/col sums of M=X*A and X, reading Xt (d-contiguous -> coalesced) ----
__global__ __launch_bounds__(256) void k_rowcol(const u16* __restrict__ Xt, const float* __restrict__ A,
                         float* __restrict__ RM, float* __restrict__ CM,
                         float* __restrict__ RX, float* __restrict__ CXv){
  int b = blockIdx.y;
  int t = threadIdx.x;
  int d = t & 63;
  int task = blockIdx.x*4 + (t >> 6);
  float sm = 0.f, sx = 0.f;
  if (task < 128){
    int i = task;
    for (int j = 0; j < 128; j++){
      float xv = b2f(Xt[((size_t)(b*16384 + i*128 + j))*64 + d]);
      float av = A[b*16384 + i*128 + j];
      sm += xv*av; sx += xv;
    }
    RM[(b*64 + d)*128 + i] = sm;
    RX[(b*64 + d)*128 + i] = sx;
  } else {
    int j = task - 128;
    for (int i = 0; i < 128; i++){
      float xv = b2f(Xt[((size_t)(b*16384 + i*128 + j))*64 + d]);
      float av = A[b*16384 + i*128 + j];
      sm += xv*av; sx += xv;
    }
    CM[(b*64 + d)*128 + j] = sm;
    CXv[(b*64 + d)*128 + j] = sx;
  }
}

// ---- MFMA channel-mix: P_s = W_s^T X ; epilogue combines into Ua..Ud (bf16) / Yacc (fp32) ----
__global__ __launch_bounds__(256) void k_mix(const u16* __restrict__ Xt, const float* __restrict__ A,
    const float* __restrict__ AAt, const float* __restrict__ rA, const u16* __restrict__ Wb,
    u16* __restrict__ Ua, u16* __restrict__ Ub, u16* __restrict__ Uc, u16* __restrict__ Ud,
    float* __restrict__ Yacc)
{
  const int b = blockIdx.y, g = blockIdx.z;
  const int t = threadIdx.x;
  const int wave = t >> 6, lane = t & 63;
  const int col = lane & 15, quad = lane >> 4;
  const int ij = blockIdx.x*64 + wave*16 + col;

  const u16* xp = Xt + ((size_t)(b*16384 + ij))*64 + quad*8;
  short8 xb0 = *(const short8*)xp;
  short8 xb1 = *(const short8*)(xp + 32);

  int s0, nsl;
  if (g == 0){ s0 = 0; nsl = 2; }
  else if (g == 1){ s0 = 2; nsl = 2; }
  else if (g == 2){ s0 = 4; nsl = 1; }
  else if (g == 3){ s0 = 5; nsl = 1; }
  else { s0 = 6; nsl = 4; }

  f32x4 acc[4][4];
  #pragma unroll
  for (int s = 0; s < 4; s++)
    #pragma unroll
    for (int et = 0; et < 4; et++)
      acc[s][et] = (f32x4){0.f,0.f,0.f,0.f};

  for (int s = 0; s < nsl; s++){
    #pragma unroll
    for (int et = 0; et < 4; et++){
      const u16* wp = Wb + ((size_t)((s0 + s)*64 + et*16 + col))*64 + quad*8;
      short8 a0 = *(const short8*)wp;
      short8 a1 = *(const short8*)(wp + 32);
      acc[s][et] = MFMA16(a0, xb0, acc[s][et]);
      acc[s][et] = MFMA16(a1, xb1, acc[s][et]);
    }
  }

  const float a_s = A[b*16384 + ij];
  if (g < 4){
    u16* U = (g==0)?Ua:(g==1)?Ub:(g==2)?Uc:Ud;
    #pragma unroll
    for (int et = 0; et < 4; et++){
      #pragma unroll
      for (int r = 0; r < 4; r++){
        float v = acc[0][et][r]*a_s + acc[1][et][r];   // acc[1]==0 for nsl==1
        int row = et*16 + quad*4 + r;
        U[(((size_t)(b*64 + row)) << 14) + ij] = f2b(v);
      }
    }
  } else {
    const float t_s = AAt[b*16384 + ij];
    const int i = ij >> 7, j = ij & 127;
    const float ri = rA[b*128 + i], rj = rA[b*128 + j];
    #pragma unroll
    for (int et = 0; et < 4; et++){
      #pragma unroll
      for (int r = 0; r < 4; r++){
        float v = acc[0][et][r]*t_s + acc[1][et][r]*ri + acc[2][et][r]*rj + acc[3][et][r];
        int row = et*16 + quad*4 + r;
        Yacc[(((size_t)(b*64 + row)) << 14) + ij] = v;
      }
    }
  }
}

// ---- MFMA: the four A-products, K=512 fused, Yacc += ----
__global__ __launch_bounds__(256) void k_tn(const u16* __restrict__ ATb,
    const u16* __restrict__ UaT, const u16* __restrict__ UbT,
    const u16* __restrict__ Uc, const u16* __restrict__ Ud,
    float* __restrict__ Yacc)
{
  const int blk = blockIdx.x;       // 1024
  const int be = blk >> 2, q = blk & 3;
  const int b = be >> 6;
  const int t = threadIdx.x;
  const int wave = t >> 6, lane = t & 63;
  const int col = lane & 15, quad = lane >> 4;
  const int m0 = (q >> 1)*64 + (wave >> 1)*32;
  const int n0 = (q & 1)*64 + (wave & 1)*32;

  const u16* at  = ATb + (((size_t)b) << 14);
  const u16* uat = UaT + (((size_t)be) << 14);
  const u16* ubt = UbT + (((size_t)be) << 14);
  const u16* uc  = Uc  + (((size_t)be) << 14);
  const u16* ud  = Ud  + (((size_t)be) << 14);
  const u16* sa_t[4] = {uat, at, uc, at};
  const u16* rb_t[4] = {at, ubt, at, ud};

  f32x4 acc[2][2];
  #pragma unroll
  for (int et = 0; et < 2; et++)
    #pragma unroll
    for (int nt = 0; nt < 2; nt++)
      acc[et][nt] = (f32x4){0.f,0.f,0.f,0.f};

  for (int f = 0; f < 4; f++){
    const u16* sa = sa_t[f];
    const u16* rb = rb_t[f];
    #pragma unroll
    for (int kq = 0; kq < 4; kq++){
      int k0 = kq*32 + quad*8;
      short8 a0 = *(const short8*)(sa + (m0 + col)*128 + k0);
      short8 a1 = *(const short8*)(sa + (m0 + 16 + col)*128 + k0);
      short8 b0 = *(const short8*)(rb + (n0 + col)*128 + k0);
      short8 b1 = *(const short8*)(rb + (n0 + 16 + col)*128 + k0);
      acc[0][0] = MFMA16(a0, b0, acc[0][0]);
      acc[0][1] = MFMA16(a0, b1, acc[0][1]);
      acc[1][0] = MFMA16(a1, b0, acc[1][0]);
      acc[1][1] = MFMA16(a1, b1, acc[1][1]);
    }
  }
  #pragma unroll
  for (int et = 0; et < 2; et++)
    #pragma unroll
    for (int nt = 0; nt < 2; nt++)
      #pragma unroll
      for (int r = 0; r < 4; r++){
        int row = m0 + et*16 + quad*4 + r;
        int cc  = n0 + nt*16 + col;
        Yacc[(((size_t)be) << 14) + row*128 + cc] += acc[et][nt][r];
      }
}

// ---- epilogue (unchanged from round 2) ----
__global__ __launch_bounds__(256) void k_epi(const float* __restrict__ Yacc, const float* __restrict__ W,
    const float* __restrict__ RM, const float* __restrict__ CM,
    const float* __restrict__ RX, const float* __restrict__ CXv,
    const float* __restrict__ bias, u16* __restrict__ Xout, float* __restrict__ acc4, int last)
{
  const int be = blockIdx.x;
  const int b = be >> 6, e = be & 63;
  __shared__ float radd[128], cadd[128];
  __shared__ float red[4];
  const int t = threadIdx.x;
  if (t < 128){
    int i = t; float s = 0.f;
    for (int d = 0; d < ND; d++){
      int v = (b*ND + d)*NN + i;
      s += W[(640 + d)*64 + e]*RM[v] + W[(704 + d)*64 + e]*CM[v]
         + W[(768 + d)*64 + e]*RX[v] + W[(832 + d)*64 + e]*CXv[v];
    }
    radd[i] = s;
  } else {
    int j = t - 128; float s = 0.f;
    for (int d = 0; d < ND; d++){
      int v = (b*ND + d)*NN + j;
      s += W[(896 + d)*64 + e]*RM[v] + W[(960 + d)*64 + e]*CM[v]
         + W[(1024 + d)*64 + e]*RX[v] + W[(1088 + d)*64 + e]*CXv[v];
    }
    cadd[j] = s;
  }
  __syncthreads();
  const float bv = bias[e];
  const float* Y = Yacc + ((size_t)be << 14);
  if (!last){
    u16* Xo = Xout + ((size_t)be << 14);
    for (int l = 0; l < 64; l++){
      int idx = l*256 + t;
      int ii = idx >> 7, jj = idx & 127;
      float v = Y[idx] + radd[ii] + cadd[jj] + bv;
      v = 1.f/(1.f + __expf(-v));
      Xo[idx] = f2b(v);
    }
  } else {
    float loc = 0.f;
    for (int l = 0; l < 64; l++){
      int idx = l*256 + t;
      int ii = idx >> 7, jj = idx & 127;
      loc += Y[idx] + radd[ii] + cadd[jj] + bv;
    }
    for (int off = 32; off > 0; off >>= 1) loc += __shfl_down(loc, off, 64);
    if ((t & 63) == 0) red[t >> 6] = loc;
    __syncthreads();
    if (t == 0) atomicAdd(&acc4[b], red[0] + red[1] + red[2] + red[3]);
  }
}

__global__ void k_finish(const float* __restrict__ acc4, const int* __restrict__ flag,
                         void* __restrict__ out){
  int b = threadIdx.x;
  if (b >= NB) return;
  float v = acc4[b] * (1.0f/1048576.0f);
  if (*flag) ((float*)out)[b] = v;
  else       ((u16*)out)[b] = f2b(v);
}

extern "C" void kernel_launch(void* const* d_in, const int* in_sizes, int n_in,
                              void* d_out, int out_size, void* d_ws, size_t ws_size,
                              hipStream_t stream)
{
  const void* x   = d_in[0];
  const void* ew  = d_in[1];
  const void* c1  = d_in[2];
  const void* b1  = d_in[3];
  const void* c2  = d_in[4];
  const void* b2  = d_in[5];
  const int* ei  = (const int*)d_in[6];
  const int* bat = (const int*)d_in[7];
  const int E = in_sizes[1];

  char* wsb = (char*)d_ws;
  float* A    = (float*)(wsb + OFF_A);
  float* acc4 = (float*)(wsb + OFF_ACC);
  float* AAt  = (float*)(wsb + OFF_AAT);
  float* rA   = (float*)(wsb + OFF_RA);
  float* W    = (float*)(wsb + OFF_W);
  float* RM   = (float*)(wsb + OFF_RM);
  float* CM   = (float*)(wsb + OFF_CM);
  float* RX   = (float*)(wsb + OFF_RX);
  float* CXv  = (float*)(wsb + OFF_CX);
  int*   flag = (int*)(wsb + OFF_FLAG);
  float* bfv  = (float*)(wsb + OFF_BF);
  u16* ATb = (u16*)(wsb + OFF_ATB);
  u16* Wb  = (u16*)(wsb + OFF_WB);
  u16* X2  = (u16*)(wsb + OFF_X2);
  u16* Xt  = (u16*)(wsb + OFF_XT);
  u16* Ua  = (u16*)(wsb + OFF_UA);
  u16* Ub  = (u16*)(wsb + OFF_UB);
  u16* Uc  = (u16*)(wsb + OFF_UC);
  u16* Ud  = (u16*)(wsb + OFF_UD);
  u16* UaT = (u16*)(wsb + OFF_UAT);
  u16* UbT = (u16*)(wsb + OFF_UBT);
  float* Yacc = (float*)(wsb + OFF_YACC);
  float* xf   = (float*)(wsb + OFF_XF);
  float* ewf  = (float*)(wsb + OFF_EWF);
  float* cf   = (float*)(wsb + OFF_CF);

  hipMemsetAsync(wsb, 0, OFF_AAT, stream);          // zero A + acc4
  hipMemsetAsync(wsb + OFF_FLAG, 0, 256, stream);   // zero flag

  k_detect<<<dim3(1), dim3(256), 0, stream>>>((const u16*)x, flag);
  k_convert<<<dim3(737), dim3(256), 0, stream>>>(x, ew, c1, c2, b1, b2, flag, xf, ewf, cf, bfv);
  k_scatter<<<dim3((E + 255)/256), dim3(256), 0, stream>>>(ei, bat, ewf, A, E);
  k_rA<<<dim3(NB), dim3(128), 0, stream>>>(A, rA);
  k_AAt<<<dim3(8, NB), dim3(256), 0, stream>>>(A, AAt);
  k_at<<<dim3(NB), dim3(256), 0, stream>>>(A, ATb);
  k_makeXt1<<<dim3(NMAT/256), dim3(256), 0, stream>>>(xf, Xt);
  k_buildW<<<dim3(576), dim3(256), 0, stream>>>(cf, W, Wb);

  for (int L = 0; L < 2; L++){
    const float* Wl = W + (size_t)L*1152*64;
    const u16*  Wbl = Wb + (size_t)L*10*64*64;
    if (L == 1)
      k_xt<<<dim3(256, NB), dim3(256), 0, stream>>>(X2, Xt);
    k_rowcol<<<dim3(64, NB), dim3(256), 0, stream>>>(Xt, A, RM, CM, RX, CXv);
    k_mix<<<dim3(256, NB, 5), dim3(256), 0, stream>>>(Xt, A, AAt, rA, Wbl, Ua, Ub, Uc, Ud, Yacc);
    k_ut<<<dim3(256, 2), dim3(256), 0, stream>>>(Ua, Ub, UaT, UbT);
    k_tn<<<dim3(1024), dim3(256), 0, stream>>>(ATb, UaT, UbT, Uc, Ud, Yacc);
    k_epi<<<dim3(256), dim3(256), 0, stream>>>(Yacc, Wl, RM, CM, RX, CXv, bfv + L*64, X2, acc4, L);
  }
  k_finish<<<dim3(1), dim3(64), 0, stream>>>(acc4, flag, d_out);
}

// Round 4
// 355.405 us; speedup vs baseline: 2.1829x; 1.4544x over previous
//
#include <hip/hip_runtime.h>
#include <stdint.h>

typedef unsigned short u16;
using short8 = __attribute__((ext_vector_type(8))) short;
using f32x4  = __attribute__((ext_vector_type(4))) float;

#define NB 4
#define NN 128
#define NF 32
#define ND 64
#define NMAT (NB*ND*NN*NN)   // 4,194,304

// ---- workspace byte offsets ----
#define OFF_A     0u           // fp32 [4][16384]
#define OFF_ACC   262144u      // fp32 [4] (+pad)
#define OFF_AAT   262400u      // fp32 [4][16384]
#define OFF_RA    524544u      // fp32 [4][128]
#define OFF_W     526592u      // fp32 [2][1152][64]
#define OFF_RM    1116416u     // fp32 [4][64][128]
#define OFF_CM    1247488u
#define OFF_RX    1378560u
#define OFF_CX    1509632u
#define OFF_FLAG  1640704u     // int (+pad)
#define OFF_BF    1640960u     // fp32 128 (+pad)
#define OFF_ATB   1641472u     // bf16 [4][128n][128k]  (A^T, k-contig)
#define OFF_WB    1772544u     // bf16 [2][10][64e][64d]
#define OFF_X2    1936384u     // bf16 NMAT   (aliases UAT)
#define OFF_XT    10324992u    // bf16 [4][16384 ij][64 d]  (aliases UBT)
#define OFF_UA    18713600u    // bf16 NMAT
#define OFF_UB    27102208u
#define OFF_UC    35490816u
#define OFF_UD    43879424u
#define OFF_YACC  52268032u    // fp32 NMAT  (end 69,045,248)
// convert scratch aliased INTO Yacc region (dead before first Yacc write):
#define OFF_XF    (OFF_YACC)            // fp32 16384
#define OFF_EWF   (OFF_YACC + 65536u)   // fp32 8192
#define OFF_CF    (OFF_YACC + 98304u)   // fp32 2*81920
#define OFF_UAT   OFF_X2
#define OFF_UBT   OFF_XT

__device__ __forceinline__ float b2f(u16 v){
  union { uint32_t u; float f; } x; x.u = ((uint32_t)v) << 16; return x.f;
}
__device__ __forceinline__ u16 f2b(float f){
  union { uint32_t u; float f2; } x; x.f2 = f;
  uint32_t u = x.u;
  return (u16)((u + 0x7FFFu + ((u >> 16) & 1u)) >> 16);
}

#define MFMA16(a,b,c) __builtin_amdgcn_mfma_f32_16x16x32_bf16((a),(b),(c),0,0,0)

__device__ __constant__ signed char dR1[18] = {0,9,1,10,2,3,4,13,14,19,5,7,15,18,6,8,16,17};
__device__ __constant__ signed char dR2[18] = {-1,11,-1,12,-1,-1,-1,-1,-1,-1,-1,-1,-1,-1,-1,-1,-1,-1};

// ---- dtype detect (kept for robustness) ----
__global__ void k_detect(const u16* __restrict__ x16, int* __restrict__ flag){
  int t = threadIdx.x;
  int hit = 0;
  for (int k = t; k < 16384; k += 256){
    u16 u = x16[k];
    int e = (u >> 7) & 0xFF;
    if (e >= 0x90) hit = 1;
  }
  if (hit) atomicOr(flag, 1);
}

__global__ void k_convert(const void* __restrict__ xs, const void* __restrict__ ews,
                          const void* __restrict__ c1s, const void* __restrict__ c2s,
                          const void* __restrict__ b1s, const void* __restrict__ b2s,
                          const int* __restrict__ flag,
                          float* __restrict__ xf, float* __restrict__ ewf,
                          float* __restrict__ cf, float* __restrict__ bfv){
  int t = blockIdx.x*256 + threadIdx.x;
  if (t >= 188544) return;
  int isf = *flag;
  const void* src; int idx; float* dst;
  if (t < 16384)      { src = xs;  idx = t;          dst = xf + idx; }
  else if (t < 24576) { src = ews; idx = t - 16384;  dst = ewf + idx; }
  else if (t < 106496){ src = c1s; idx = t - 24576;  dst = cf + idx; }
  else if (t < 188416){ src = c2s; idx = t - 106496; dst = cf + 81920 + idx; }
  else if (t < 188480){ src = b1s; idx = t - 188416; dst = bfv + idx; }
  else                { src = b2s; idx = t - 188480; dst = bfv + 64 + idx; }
  float v = isf ? ((const float*)src)[idx] : b2f(((const u16*)src)[idx]);
  *dst = v;
}

__global__ void k_scatter(const int* __restrict__ ei, const int* __restrict__ bat,
                          const float* __restrict__ ew, float* __restrict__ A, int E){
  int t = blockIdx.x*256 + threadIdx.x;
  if (t >= E) return;
  int s = ei[t], dnode = ei[E + t];
  int g = bat[s];
  int r = s - g*NN, c = dnode - g*NN;
  atomicAdd(&A[(g*NN + r)*NN + c], ew[t]);
}

__global__ void k_rA(const float* __restrict__ A, float* __restrict__ rA){
  int b = blockIdx.x, i = threadIdx.x;
  const float* Ab = A + (b*NN + i)*NN;
  float s = 0.f;
  for (int j = 0; j < NN; j++) s += Ab[j];
  rA[b*NN + i] = s;
}

__global__ __launch_bounds__(256) void k_AAt(const float* __restrict__ A, float* __restrict__ AAt){
  int b = blockIdx.y, iq = blockIdx.x;
  int t = threadIdx.x;
  int j = t & 127, ih = t >> 7;
  const float* Ab = A + b*NN*NN;
  float acc[8] = {0,0,0,0,0,0,0,0};
  for (int k = 0; k < NN; k++){
    float aj = Ab[j*NN + k];
    #pragma unroll
    for (int ii = 0; ii < 8; ii++){
      int i = iq*16 + ih*8 + ii;
      acc[ii] += Ab[i*NN + k] * aj;
    }
  }
  #pragma unroll
  for (int ii = 0; ii < 8; ii++){
    int i = iq*16 + ih*8 + ii;
    AAt[(b*NN + i)*NN + j] = acc[ii];
  }
}

// ---- ATb[b][n][k] = bf16(A[b][k][n]) ----
__global__ __launch_bounds__(256) void k_at(const float* __restrict__ A, u16* __restrict__ ATb){
  int b = blockIdx.x;
  __shared__ float lds[128][129];
  int t = threadIdx.x;
  for (int l = 0; l < 64; l++){
    int idx = l*256 + t;
    lds[idx >> 7][idx & 127] = A[b*16384 + idx];
  }
  __syncthreads();
  for (int l = 0; l < 64; l++){
    int idx = l*256 + t;
    int r = idx >> 7, c = idx & 127;
    ATb[b*16384 + idx] = f2b(lds[c][r]);
  }
}

// ---- layer-1 Xt[b][ij][d] directly from x ----
__global__ void k_makeXt1(const float* __restrict__ xf, u16* __restrict__ Xt){
  int idx = blockIdx.x*256 + threadIdx.x;
  if (idx >= NMAT) return;
  int d = idx & 63, ij = (idx >> 6) & 16383, b = idx >> 20;
  int i = ij >> 7, j = ij & 127;
  float v = (d < NF) ? xf[(b*NN + i)*NF + d] : xf[(b*NN + j)*NF + (d - NF)];
  Xt[idx] = f2b(v);
}

// ---- X[b][e][ij] -> Xt[b][ij][e] via LDS tiles ----
__global__ __launch_bounds__(256) void k_xt(const u16* __restrict__ X, u16* __restrict__ Xt){
  int b = blockIdx.y;
  int ij0 = blockIdx.x*64;
  __shared__ u16 lds[64][65];
  int t = threadIdx.x;
  #pragma unroll
  for (int l = 0; l < 2; l++){
    int idx = l*2048 + t*8;
    int d = idx >> 6, c = idx & 63;
    const u16* p = X + ((size_t)(b*64 + d))*16384 + ij0 + c;
    short8 v = *(const short8*)p;
    #pragma unroll
    for (int k = 0; k < 8; k++) lds[d][c + k] = (u16)v[k];
  }
  __syncthreads();
  #pragma unroll
  for (int l = 0; l < 2; l++){
    int idx = l*2048 + t*8;
    int r = idx >> 6, c = idx & 63;
    short8 v;
    #pragma unroll
    for (int k = 0; k < 8; k++) v[k] = (short)lds[c + k][r];
    *(short8*)(Xt + ((size_t)(b*16384 + ij0 + r))*64 + c) = v;
  }
}

// ---- per-be 128x128 transpose: Ua->UaT, Ub->UbT ----
__global__ __launch_bounds__(256) void k_ut(const u16* __restrict__ Ua, const u16* __restrict__ Ub,
                                            u16* __restrict__ UaT, u16* __restrict__ UbT){
  int be = blockIdx.x;
  const u16* src = blockIdx.y ? Ub : Ua;
  u16* dst = blockIdx.y ? UbT : UaT;
  src += ((size_t)be) << 14; dst += ((size_t)be) << 14;
  __shared__ u16 lds[128][129];
  int t = threadIdx.x;
  #pragma unroll
  for (int l = 0; l < 8; l++){
    int idx = l*2048 + t*8;
    int r = idx >> 7, c = idx & 127;
    short8 v = *(const short8*)(src + r*128 + c);
    #pragma unroll
    for (int k = 0; k < 8; k++) lds[r][c + k] = (u16)v[k];
  }
  __syncthreads();
  #pragma unroll
  for (int l = 0; l < 8; l++){
    int idx = l*2048 + t*8;
    int r = idx >> 7, c = idx & 127;
    short8 v;
    #pragma unroll
    for (int k = 0; k < 8; k++) v[k] = (short)lds[c + k][r];
    *(short8*)(dst + r*128 + c) = v;
  }
}

// ---- W fp32 + bf16 Wb[L][slot<10][e][d] ----
__global__ void k_buildW(const float* __restrict__ cf, float* __restrict__ W, u16* __restrict__ Wb){
  int gl = blockIdx.x*256 + threadIdx.x;
  if (gl >= 2*1152*64) return;
  int L = gl / (1152*64);
  int rem = gl - L*1152*64;
  int row = rem >> 6, e = rem & 63;
  int slot = row >> 6, d = row & 63;
  const float* cc = cf + L*81920;
  int base = (d*64 + e)*20;
  float v = cc[base + dR1[slot]];
  if (dR2[slot] >= 0) v += cc[base + dR2[slot]];
  float scale = (slot == 9) ? 1.0f : (1.0f/128.0f);
  v *= scale;
  W[gl] = v;
  if (slot < 10)
    Wb[(((size_t)L*10 + slot)*64 + e)*64 + d] = f2b(v);
}

// ---- row/col sums of M=X*A and X ----
__global__ __launch_bounds__(256) void k_rowcol(const u16* __restrict__ Xt, const float* __restrict__ A,
                         float* __restrict__ RM, float* __restrict__ CM,
                         float* __restrict__ RX, float* __restrict__ CXv){
  int b = blockIdx.y;
  int t = threadIdx.x;
  int d = t & 63;
  int task = blockIdx.x*4 + (t >> 6);
  float sm = 0.f, sx = 0.f;
  if (task < 128){
    int i = task;
    for (int j = 0; j < 128; j++){
      float xv = b2f(Xt[((size_t)(b*16384 + i*128 + j))*64 + d]);
      float av = A[b*16384 + i*128 + j];
      sm += xv*av; sx += xv;
    }
    RM[(b*64 + d)*128 + i] = sm;
    RX[(b*64 + d)*128 + i] = sx;
  } else {
    int j = task - 128;
    for (int i = 0; i < 128; i++){
      float xv = b2f(Xt[((size_t)(b*16384 + i*128 + j))*64 + d]);
      float av = A[b*16384 + i*128 + j];
      sm += xv*av; sx += xv;
    }
    CM[(b*64 + d)*128 + j] = sm;
    CXv[(b*64 + d)*128 + j] = sx;
  }
}

#define SLDS 69   // fp32 LDS row stride: <=2-way bank aliasing on b128 reads

__device__ __forceinline__ void mix_slots(int s0, int nsl, const u16* __restrict__ Wb,
                                          short8 xb0, short8 xb1, int col, int quad,
                                          f32x4 acc[4][4]){
  for (int s = 0; s < nsl; s++){
    #pragma unroll
    for (int et = 0; et < 4; et++){
      const u16* wp = Wb + ((size_t)((s0 + s)*64 + et*16 + col))*64 + quad*8;
      short8 a0 = *(const short8*)wp;
      short8 a1 = *(const short8*)(wp + 32);
      acc[s][et] = MFMA16(a0, xb0, acc[s][et]);
      acc[s][et] = MFMA16(a1, xb1, acc[s][et]);
    }
  }
}

// ---- MFMA channel-mix, fused all 10 slots, LDS-staged coalesced writes ----
__global__ __launch_bounds__(256) void k_mix(const u16* __restrict__ Xt, const float* __restrict__ A,
    const float* __restrict__ AAt, const float* __restrict__ rA, const u16* __restrict__ Wb,
    u16* __restrict__ Ua, u16* __restrict__ Ub, u16* __restrict__ Uc, u16* __restrict__ Ud,
    float* __restrict__ Yacc)
{
  const int b = blockIdx.y;
  const int t = threadIdx.x;
  const int wave = t >> 6, lane = t & 63;
  const int col = lane & 15, quad = lane >> 4;
  const int ij0 = blockIdx.x*64;
  const int ij = ij0 + wave*16 + col;

  __shared__ float lds[64*SLDS];

  const u16* xp = Xt + ((size_t)(b*16384 + ij))*64 + quad*8;
  short8 xb0 = *(const short8*)xp;
  short8 xb1 = *(const short8*)(xp + 32);

  const float a_s = A[b*16384 + ij];
  const float t_s = AAt[b*16384 + ij];
  const int ii = ij >> 7, jj = ij & 127;
  const float ri = rA[b*128 + ii], rj = rA[b*128 + jj];

  // writeout mapping: e = t>>2, seg = t&3 (16 ij each)
  const int eo = t >> 2, seg = t & 3;
  const float* lp = lds + eo*SLDS + seg*16;

  f32x4 acc[4][4];

  #pragma unroll
  for (int g = 0; g < 5; g++){
    const int s0_tab[5]  = {0, 2, 4, 5, 6};
    const int nsl_tab[5] = {2, 2, 1, 1, 4};
    int s0 = s0_tab[g], nsl = nsl_tab[g];
    #pragma unroll
    for (int s = 0; s < 4; s++)
      #pragma unroll
      for (int et = 0; et < 4; et++)
        acc[s][et] = (f32x4){0.f,0.f,0.f,0.f};
    mix_slots(s0, nsl, Wb, xb0, xb1, col, quad, acc);

    // combine + stage to LDS (fp32, stride SLDS)
    #pragma unroll
    for (int et = 0; et < 4; et++){
      #pragma unroll
      for (int r = 0; r < 4; r++){
        float v;
        if (g == 0 || g == 1)      v = acc[0][et][r]*a_s + acc[1][et][r];
        else if (g == 2 || g == 3) v = acc[0][et][r]*a_s;
        else v = acc[0][et][r]*t_s + acc[1][et][r]*ri + acc[2][et][r]*rj + acc[3][et][r];
        int row = et*16 + quad*4 + r;
        lds[row*SLDS + wave*16 + col] = v;
      }
    }
    __syncthreads();

    if (g < 4){
      u16* U = (g==0)?Ua:(g==1)?Ub:(g==2)?Uc:Ud;
      short8 v0, v1;
      #pragma unroll
      for (int k = 0; k < 8; k++){ v0[k] = (short)f2b(lp[k]); v1[k] = (short)f2b(lp[8+k]); }
      u16* dst = U + ((size_t)(b*64 + eo) << 14) + ij0 + seg*16;
      *(short8*)dst = v0;
      *(short8*)(dst + 8) = v1;
    } else {
      float* dst = Yacc + ((size_t)(b*64 + eo) << 14) + ij0 + seg*16;
      #pragma unroll
      for (int q = 0; q < 4; q++){
        float4 v = make_float4(lp[q*4+0], lp[q*4+1], lp[q*4+2], lp[q*4+3]);
        *(float4*)(dst + q*4) = v;
      }
    }
    __syncthreads();
  }
}

// ---- MFMA: the four A-products, K=512 fused, Yacc += ----
__global__ __launch_bounds__(256) void k_tn(const u16* __restrict__ ATb,
    const u16* __restrict__ UaT, const u16* __restrict__ UbT,
    const u16* __restrict__ Uc, const u16* __restrict__ Ud,
    float* __restrict__ Yacc)
{
  const int blk = blockIdx.x;       // 1024
  const int be = blk >> 2, q = blk & 3;
  const int b = be >> 6;
  const int t = threadIdx.x;
  const int wave = t >> 6, lane = t & 63;
  const int col = lane & 15, quad = lane >> 4;
  const int m0 = (q >> 1)*64 + (wave >> 1)*32;
  const int n0 = (q & 1)*64 + (wave & 1)*32;

  const u16* at  = ATb + (((size_t)b) << 14);
  const u16* uat = UaT + (((size_t)be) << 14);
  const u16* ubt = UbT + (((size_t)be) << 14);
  const u16* uc  = Uc  + (((size_t)be) << 14);
  const u16* ud  = Ud  + (((size_t)be) << 14);
  const u16* sa_t[4] = {uat, at, uc, at};
  const u16* rb_t[4] = {at, ubt, at, ud};

  f32x4 acc[2][2];
  #pragma unroll
  for (int et = 0; et < 2; et++)
    #pragma unroll
    for (int nt = 0; nt < 2; nt++)
      acc[et][nt] = (f32x4){0.f,0.f,0.f,0.f};

  for (int f = 0; f < 4; f++){
    const u16* sa = sa_t[f];
    const u16* rb = rb_t[f];
    #pragma unroll
    for (int kq = 0; kq < 4; kq++){
      int k0 = kq*32 + quad*8;
      short8 a0 = *(const short8*)(sa + (m0 + col)*128 + k0);
      short8 a1 = *(const short8*)(sa + (m0 + 16 + col)*128 + k0);
      short8 b0 = *(const short8*)(rb + (n0 + col)*128 + k0);
      short8 b1 = *(const short8*)(rb + (n0 + 16 + col)*128 + k0);
      acc[0][0] = MFMA16(a0, b0, acc[0][0]);
      acc[0][1] = MFMA16(a0, b1, acc[0][1]);
      acc[1][0] = MFMA16(a1, b0, acc[1][0]);
      acc[1][1] = MFMA16(a1, b1, acc[1][1]);
    }
  }
  #pragma unroll
  for (int et = 0; et < 2; et++)
    #pragma unroll
    for (int nt = 0; nt < 2; nt++)
      #pragma unroll
      for (int r = 0; r < 4; r++){
        int row = m0 + et*16 + quad*4 + r;
        int cc  = n0 + nt*16 + col;
        Yacc[(((size_t)be) << 14) + row*128 + cc] += acc[et][nt][r];
      }
}

// ---- epilogue ----
__global__ __launch_bounds__(256) void k_epi(const float* __restrict__ Yacc, const float* __restrict__ W,
    const float* __restrict__ RM, const float* __restrict__ CM,
    const float* __restrict__ RX, const float* __restrict__ CXv,
    const float* __restrict__ bias, u16* __restrict__ Xout, float* __restrict__ acc4, int last)
{
  const int be = blockIdx.x;
  const int b = be >> 6, e = be & 63;
  __shared__ float radd[128], cadd[128];
  __shared__ float red[4];
  const int t = threadIdx.x;
  if (t < 128){
    int i = t; float s = 0.f;
    for (int d = 0; d < ND; d++){
      int v = (b*ND + d)*NN + i;
      s += W[(640 + d)*64 + e]*RM[v] + W[(704 + d)*64 + e]*CM[v]
         + W[(768 + d)*64 + e]*RX[v] + W[(832 + d)*64 + e]*CXv[v];
    }
    radd[i] = s;
  } else {
    int j = t - 128; float s = 0.f;
    for (int d = 0; d < ND; d++){
      int v = (b*ND + d)*NN + j;
      s += W[(896 + d)*64 + e]*RM[v] + W[(960 + d)*64 + e]*CM[v]
         + W[(1024 + d)*64 + e]*RX[v] + W[(1088 + d)*64 + e]*CXv[v];
    }
    cadd[j] = s;
  }
  __syncthreads();
  const float bv = bias[e];
  const float* Y = Yacc + ((size_t)be << 14);
  if (!last){
    u16* Xo = Xout + ((size_t)be << 14);
    for (int l = 0; l < 64; l++){
      int idx = l*256 + t;
      int ii = idx >> 7, jj = idx & 127;
      float v = Y[idx] + radd[ii] + cadd[jj] + bv;
      v = 1.f/(1.f + __expf(-v));
      Xo[idx] = f2b(v);
    }
  } else {
    float loc = 0.f;
    for (int l = 0; l < 64; l++){
      int idx = l*256 + t;
      int ii = idx >> 7, jj = idx & 127;
      loc += Y[idx] + radd[ii] + cadd[jj] + bv;
    }
    for (int off = 32; off > 0; off >>= 1) loc += __shfl_down(loc, off, 64);
    if ((t & 63) == 0) red[t >> 6] = loc;
    __syncthreads();
    if (t == 0) atomicAdd(&acc4[b], red[0] + red[1] + red[2] + red[3]);
  }
}

__global__ void k_finish(const float* __restrict__ acc4, const int* __restrict__ flag,
                         void* __restrict__ out){
  int b = threadIdx.x;
  if (b >= NB) return;
  float v = acc4[b] * (1.0f/1048576.0f);
  if (*flag) ((float*)out)[b] = v;
  else       ((u16*)out)[b] = f2b(v);
}

extern "C" void kernel_launch(void* const* d_in, const int* in_sizes, int n_in,
                              void* d_out, int out_size, void* d_ws, size_t ws_size,
                              hipStream_t stream)
{
  const void* x   = d_in[0];
  const void* ew  = d_in[1];
  const void* c1  = d_in[2];
  const void* b1  = d_in[3];
  const void* c2  = d_in[4];
  const void* b2  = d_in[5];
  const int* ei  = (const int*)d_in[6];
  const int* bat = (const int*)d_in[7];
  const int E = in_sizes[1];

  char* wsb = (char*)d_ws;
  float* A    = (float*)(wsb + OFF_A);
  float* acc4 = (float*)(wsb + OFF_ACC);
  float* AAt  = (float*)(wsb + OFF_AAT);
  float* rA   = (float*)(wsb + OFF_RA);
  float* W    = (float*)(wsb + OFF_W);
  float* RM   = (float*)(wsb + OFF_RM);
  float* CM   = (float*)(wsb + OFF_CM);
  float* RX   = (float*)(wsb + OFF_RX);
  float* CXv  = (float*)(wsb + OFF_CX);
  int*   flag = (int*)(wsb + OFF_FLAG);
  float* bfv  = (float*)(wsb + OFF_BF);
  u16* ATb = (u16*)(wsb + OFF_ATB);
  u16* Wb  = (u16*)(wsb + OFF_WB);
  u16* X2  = (u16*)(wsb + OFF_X2);
  u16* Xt  = (u16*)(wsb + OFF_XT);
  u16* Ua  = (u16*)(wsb + OFF_UA);
  u16* Ub  = (u16*)(wsb + OFF_UB);
  u16* Uc  = (u16*)(wsb + OFF_UC);
  u16* Ud  = (u16*)(wsb + OFF_UD);
  u16* UaT = (u16*)(wsb + OFF_UAT);
  u16* UbT = (u16*)(wsb + OFF_UBT);
  float* Yacc = (float*)(wsb + OFF_YACC);
  float* xf   = (float*)(wsb + OFF_XF);
  float* ewf  = (float*)(wsb + OFF_EWF);
  float* cf   = (float*)(wsb + OFF_CF);

  hipMemsetAsync(wsb, 0, OFF_AAT, stream);          // zero A + acc4
  hipMemsetAsync(wsb + OFF_FLAG, 0, 256, stream);   // zero flag

  k_detect<<<dim3(1), dim3(256), 0, stream>>>((const u16*)x, flag);
  k_convert<<<dim3(737), dim3(256), 0, stream>>>(x, ew, c1, c2, b1, b2, flag, xf, ewf, cf, bfv);
  k_scatter<<<dim3((E + 255)/256), dim3(256), 0, stream>>>(ei, bat, ewf, A, E);
  k_rA<<<dim3(NB), dim3(128), 0, stream>>>(A, rA);
  k_AAt<<<dim3(8, NB), dim3(256), 0, stream>>>(A, AAt);
  k_at<<<dim3(NB), dim3(256), 0, stream>>>(A, ATb);
  k_makeXt1<<<dim3(NMAT/256), dim3(256), 0, stream>>>(xf, Xt);
  k_buildW<<<dim3(576), dim3(256), 0, stream>>>(cf, W, Wb);

  for (int L = 0; L < 2; L++){
    const float* Wl = W + (size_t)L*1152*64;
    const u16*  Wbl = Wb + (size_t)L*10*64*64;
    if (L == 1)
      k_xt<<<dim3(256, NB), dim3(256), 0, stream>>>(X2, Xt);
    k_rowcol<<<dim3(64, NB), dim3(256), 0, stream>>>(Xt, A, RM, CM, RX, CXv);
    k_mix<<<dim3(256, NB), dim3(256), 0, stream>>>(Xt, A, AAt, rA, Wbl, Ua, Ub, Uc, Ud, Yacc);
    k_ut<<<dim3(256, 2), dim3(256), 0, stream>>>(Ua, Ub, UaT, UbT);
    k_tn<<<dim3(1024), dim3(256), 0, stream>>>(ATb, UaT, UbT, Uc, Ud, Yacc);
    k_epi<<<dim3(256), dim3(256), 0, stream>>>(Yacc, Wl, RM, CM, RX, CXv, bfv + L*64, X2, acc4, L);
  }
  k_finish<<<dim3(1), dim3(64), 0, stream>>>(acc4, flag, d_out);
}